// Round 1
// baseline (1155.417 us; speedup 1.0000x reference)
//
#include <hip/hip_runtime.h>
#include <stdint.h>

#define NB 8
#define CC 512
#define LL 3136
#define CIN 256

typedef __attribute__((ext_vector_type(8))) short bf8;
typedef __attribute__((ext_vector_type(4))) float f4;

__device__ __forceinline__ f4 mfma_bf16(bf8 a, bf8 b, f4 c) {
  return __builtin_amdgcn_mfma_f32_16x16x32_bf16(a, b, c, 0, 0, 0);
}

__device__ __forceinline__ unsigned short f2bf(float f) {
  unsigned int u = __float_as_uint(f);
  u += 0x7FFFu + ((u >> 16) & 1u);
  return (unsigned short)(u >> 16);
}

// ---- kernel 0a: convert weights to bf16. layout: [Wth][Wph][Wg][Wout], each 131072 elems
__global__ void k_convw(const float* Wth, const float* Wph, const float* Wg, const float* Wout,
                        unsigned short* dst) {
  int i = blockIdx.x * 256 + threadIdx.x;   // 0..524287
  int which = i >> 17;
  int off = i & 131071;
  const float* s = which == 0 ? Wth : which == 1 ? Wph : which == 2 ? Wg : Wout;
  dst[i] = f2bf(s[off]);
}

// ---- kernel 0b: transpose x (n,C,L) fp32 -> xT (n,L,C) bf16, 64x64 tiles
__global__ __launch_bounds__(256) void k_xT(const float* x, unsigned short* xT) {
  __shared__ unsigned short tile[64][66];   // stride 66 ushorts = 33 words -> conflict-free
  const int lt = blockIdx.x, n = blockIdx.y, ct = blockIdx.z;
  const int t = threadIdx.x;
  const float* xb = x + (size_t)n * CC * LL + (size_t)(ct * 64) * LL + lt * 64;
  const int tl = t & 63, trow = t >> 6;
#pragma unroll
  for (int i = 0; i < 16; ++i) {
    int c = i * 4 + trow;
    tile[c][tl] = f2bf(xb[(size_t)c * LL + tl]);
  }
  __syncthreads();
  unsigned short* xo = xT + (size_t)n * LL * CC + (size_t)(lt * 64) * CC + ct * 64;
  const int tc = t & 63, lrow = t >> 6;
#pragma unroll
  for (int i = 0; i < 16; ++i) {
    int l = i * 4 + lrow;
    xo[(size_t)l * CC + tc] = tile[tc][l];
  }
}

// ---- kernel 1: projections.
// proj 0: theta -> QT (n,L,CI)   proj 1: phi -> KT (n,L,CI)   proj 2: g -> Vb (n,CI,L)
__global__ __launch_bounds__(256) void k_proj(const unsigned short* Wbf,
    const float* bth, const float* bph, const float* bg,
    const unsigned short* xT, unsigned short* QT, unsigned short* KT, unsigned short* Vb) {
  const int lt = blockIdx.x, n = blockIdx.y, z = blockIdx.z;
  const int proj = z >> 2, cit = z & 3;
  const int wave = threadIdx.x >> 6, lane = threadIdx.x & 63;
  const int quad = lane >> 4, c16 = lane & 15;
  const unsigned short* W = Wbf + proj * 131072;
  const unsigned short* xb = xT + (size_t)n * LL * CC;
  const f4 zz = {0.f, 0.f, 0.f, 0.f};
  f4 acc[4] = {zz, zz, zz, zz};

  if (proj < 2) {
    // A = W (rows ci), B = x^T read from xT rows; C[ci][l]
    const int ciB = cit * 64 + wave * 16;
#pragma unroll
    for (int kc = 0; kc < 16; ++kc) {
      bf8 a = *(const bf8*)(W + (size_t)(ciB + c16) * CC + kc * 32 + quad * 8);
      const unsigned short* xr = xb + (size_t)(lt * 64 + c16) * CC + kc * 32 + quad * 8;
      acc[0] = mfma_bf16(a, *(const bf8*)(xr), acc[0]);
      acc[1] = mfma_bf16(a, *(const bf8*)(xr + 16 * CC), acc[1]);
      acc[2] = mfma_bf16(a, *(const bf8*)(xr + 32 * CC), acc[2]);
      acc[3] = mfma_bf16(a, *(const bf8*)(xr + 48 * CC), acc[3]);
    }
    const float* bias = proj == 0 ? bth : bph;
    unsigned short* dst = proj == 0 ? QT : KT;
    const float b0 = bias[ciB + quad * 4 + 0];
    const float b1 = bias[ciB + quad * 4 + 1];
    const float b2 = bias[ciB + quad * 4 + 2];
    const float b3 = bias[ciB + quad * 4 + 3];
#pragma unroll
    for (int cg = 0; cg < 4; ++cg) {
      int l = lt * 64 + cg * 16 + c16;
      ushort4 v;
      v.x = f2bf(acc[cg][0] + b0);
      v.y = f2bf(acc[cg][1] + b1);
      v.z = f2bf(acc[cg][2] + b2);
      v.w = f2bf(acc[cg][3] + b3);
      *(ushort4*)(dst + ((size_t)n * LL + l) * CIN + ciB + quad * 4) = v;
    }
  } else {
    // A = x^T (rows l), B = Wg^T; C[l][ci] -> store (n,CI,L)
    const int lB = lt * 64 + wave * 16;
#pragma unroll
    for (int kc = 0; kc < 16; ++kc) {
      bf8 a = *(const bf8*)(xb + (size_t)(lB + c16) * CC + kc * 32 + quad * 8);
      const unsigned short* wr = W + (size_t)(cit * 64 + c16) * CC + kc * 32 + quad * 8;
      acc[0] = mfma_bf16(a, *(const bf8*)(wr), acc[0]);
      acc[1] = mfma_bf16(a, *(const bf8*)(wr + 16 * CC), acc[1]);
      acc[2] = mfma_bf16(a, *(const bf8*)(wr + 32 * CC), acc[2]);
      acc[3] = mfma_bf16(a, *(const bf8*)(wr + 48 * CC), acc[3]);
    }
#pragma unroll
    for (int cg = 0; cg < 4; ++cg) {
      int ci = cit * 64 + cg * 16 + c16;
      float bv = bg[ci];
      ushort4 v;
      v.x = f2bf(acc[cg][0] + bv);
      v.y = f2bf(acc[cg][1] + bv);
      v.z = f2bf(acc[cg][2] + bv);
      v.w = f2bf(acc[cg][3] + bv);
      *(ushort4*)(Vb + ((size_t)n * CIN + ci) * LL + lB + quad * 4) = v;
    }
  }
}

// ---- kernel 2: flash attention. 4 waves/block, 16 queries/wave, loop 49 key tiles of 64.
__global__ __launch_bounds__(256) void k_attn(const unsigned short* QT, const unsigned short* KT,
                                              const unsigned short* Vb, unsigned short* O) {
  __shared__ __align__(16) unsigned short plds[4][16][72];  // per-wave P tile, padded
  const int qt = blockIdx.x, n = blockIdx.y;
  const int wave = threadIdx.x >> 6, lane = threadIdx.x & 63;
  const int quad = lane >> 4, c16 = lane & 15;
  const int q0 = qt * 64 + wave * 16;
  const unsigned short* Qb = QT + ((size_t)n * LL + q0) * CIN;
  const unsigned short* Kbase = KT + (size_t)n * LL * CIN;
  const unsigned short* Vbase = Vb + (size_t)n * CIN * LL;

  bf8 qf[8];
#pragma unroll
  for (int kc = 0; kc < 8; ++kc)
    qf[kc] = *(const bf8*)(Qb + (size_t)c16 * CIN + kc * 32 + quad * 8);

  const f4 zz = {0.f, 0.f, 0.f, 0.f};
  f4 o[16];
#pragma unroll
  for (int i = 0; i < 16; ++i) o[i] = zz;
  float m[4], s[4];
#pragma unroll
  for (int r = 0; r < 4; ++r) { m[r] = -1e30f; s[r] = 0.f; }

  for (int kt = 0; kt < 49; ++kt) {
    const int k0 = kt * 64;
    f4 sc[4] = {zz, zz, zz, zz};
    const unsigned short* Kb = Kbase + (size_t)k0 * CIN;
#pragma unroll
    for (int kc = 0; kc < 8; ++kc) {
      bf8 a = qf[kc];
#pragma unroll
      for (int cg = 0; cg < 4; ++cg) {
        bf8 b = *(const bf8*)(Kb + (size_t)(cg * 16 + c16) * CIN + kc * 32 + quad * 8);
        sc[cg] = mfma_bf16(a, b, sc[cg]);
      }
    }
    float pv[4][4], alpha[4];
#pragma unroll
    for (int r = 0; r < 4; ++r) {
      float s0 = sc[0][r] * 0.0625f, s1 = sc[1][r] * 0.0625f;
      float s2 = sc[2][r] * 0.0625f, s3 = sc[3][r] * 0.0625f;
      float mx = fmaxf(fmaxf(s0, s1), fmaxf(s2, s3));
#pragma unroll
      for (int off = 1; off < 16; off <<= 1) mx = fmaxf(mx, __shfl_xor(mx, off));
      float mn = fmaxf(m[r], mx);
      float al = __expf(m[r] - mn);
      float p0 = __expf(s0 - mn), p1 = __expf(s1 - mn);
      float p2 = __expf(s2 - mn), p3 = __expf(s3 - mn);
      float ps = p0 + p1 + p2 + p3;
#pragma unroll
      for (int off = 1; off < 16; off <<= 1) ps += __shfl_xor(ps, off);
      s[r] = s[r] * al + ps;
      m[r] = mn;
      alpha[r] = al;
      pv[0][r] = p0; pv[1][r] = p1; pv[2][r] = p2; pv[3][r] = p3;
    }
#pragma unroll
    for (int cg = 0; cg < 16; ++cg) {
      f4 t = o[cg];
      t[0] *= alpha[0]; t[1] *= alpha[1]; t[2] *= alpha[2]; t[3] *= alpha[3];
      o[cg] = t;
    }
    // P (C-layout) -> LDS -> A-layout
#pragma unroll
    for (int cg = 0; cg < 4; ++cg)
#pragma unroll
      for (int r = 0; r < 4; ++r)
        plds[wave][quad * 4 + r][cg * 16 + c16] = f2bf(pv[cg][r]);
    __syncthreads();
#pragma unroll
    for (int kc2 = 0; kc2 < 2; ++kc2) {
      bf8 a = *(const bf8*)(&plds[wave][c16][kc2 * 32 + quad * 8]);
#pragma unroll
      for (int cg = 0; cg < 16; ++cg) {
        bf8 b = *(const bf8*)(Vbase + (size_t)(cg * 16 + c16) * LL + k0 + kc2 * 32 + quad * 8);
        o[cg] = mfma_bf16(a, b, o[cg]);
      }
    }
    __syncthreads();
  }
  float inv[4];
#pragma unroll
  for (int r = 0; r < 4; ++r) inv[r] = 1.f / s[r];
  unsigned short* Ob = O + ((size_t)n * LL + q0) * CIN;
#pragma unroll
  for (int cg = 0; cg < 16; ++cg)
#pragma unroll
    for (int r = 0; r < 4; ++r)
      Ob[(size_t)(quad * 4 + r) * CIN + cg * 16 + c16] = f2bf(o[cg][r] * inv[r]);
}

// ---- kernel 3: out = x + b_out + W_out @ y, fp32 output
__global__ __launch_bounds__(256) void k_out(const unsigned short* O, const unsigned short* Wo,
    const float* bout, const float* x, float* out) {
  const int lt = blockIdx.x, n = blockIdx.y, ct = blockIdx.z;
  const int wave = threadIdx.x >> 6, lane = threadIdx.x & 63;
  const int quad = lane >> 4, c16 = lane & 15;
  const int lB = lt * 64 + wave * 16;
  const f4 zz = {0.f, 0.f, 0.f, 0.f};
  f4 acc[4] = {zz, zz, zz, zz};
  const unsigned short* Ob = O + (size_t)n * LL * CIN;
#pragma unroll
  for (int kc = 0; kc < 8; ++kc) {
    bf8 a = *(const bf8*)(Ob + (size_t)(lB + c16) * CIN + kc * 32 + quad * 8);
    const unsigned short* wr = Wo + (size_t)(ct * 64 + c16) * CIN + kc * 32 + quad * 8;
    acc[0] = mfma_bf16(a, *(const bf8*)(wr), acc[0]);
    acc[1] = mfma_bf16(a, *(const bf8*)(wr + 16 * CIN), acc[1]);
    acc[2] = mfma_bf16(a, *(const bf8*)(wr + 32 * CIN), acc[2]);
    acc[3] = mfma_bf16(a, *(const bf8*)(wr + 48 * CIN), acc[3]);
  }
#pragma unroll
  for (int cg = 0; cg < 4; ++cg) {
    int c = ct * 64 + cg * 16 + c16;
    float bv = bout[c];
    size_t base = ((size_t)n * CC + c) * LL + lB + quad * 4;
    f4 xv = *(const f4*)(x + base);
    f4 r;
    r[0] = xv[0] + bv + acc[cg][0];
    r[1] = xv[1] + bv + acc[cg][1];
    r[2] = xv[2] + bv + acc[cg][2];
    r[3] = xv[3] + bv + acc[cg][3];
    *(f4*)(out + base) = r;
  }
}

extern "C" void kernel_launch(void* const* d_in, const int* in_sizes, int n_in,
                              void* d_out, int out_size, void* d_ws, size_t ws_size,
                              hipStream_t stream) {
  const float* x     = (const float*)d_in[0];
  const float* W_g   = (const float*)d_in[1];
  const float* b_g   = (const float*)d_in[2];
  const float* W_th  = (const float*)d_in[3];
  const float* b_th  = (const float*)d_in[4];
  const float* W_ph  = (const float*)d_in[5];
  const float* b_ph  = (const float*)d_in[6];
  const float* W_out = (const float*)d_in[7];
  const float* b_out = (const float*)d_in[8];

  char* ws = (char*)d_ws;
  const size_t SZ_W  = 1048576;            // 4 x 131072 bf16
  const size_t SZ_P  = 12845056;           // 8*3136*256*2
  unsigned short* Wbf = (unsigned short*)(ws);
  unsigned short* QT  = (unsigned short*)(ws + SZ_W);
  unsigned short* KT  = (unsigned short*)(ws + SZ_W + SZ_P);
  unsigned short* Vb  = (unsigned short*)(ws + SZ_W + 2 * SZ_P);
  unsigned short* xT  = (unsigned short*)(ws + SZ_W + 3 * SZ_P);  // 25690112 B
  unsigned short* O   = xT;  // alias: xT dead after k_proj
  float* out = (float*)d_out;

  k_convw<<<2048, 256, 0, stream>>>(W_th, W_ph, W_g, W_out, Wbf);
  k_xT<<<dim3(49, 8, 8), 256, 0, stream>>>(x, xT);
  k_proj<<<dim3(49, 8, 12), 256, 0, stream>>>(Wbf, b_th, b_ph, b_g, xT, QT, KT, Vb);
  k_attn<<<dim3(49, 8), 256, 0, stream>>>(QT, KT, Vb, O);
  k_out<<<dim3(49, 8, 8), 256, 0, stream>>>(O, Wbf + 3 * 131072, b_out, x, out);
}